// Round 7
// baseline (169.167 us; speedup 1.0000x reference)
//
#include <hip/hip_runtime.h>
#include <math.h>

#define TOKENS 16384
#define DIM 4096
#define NE 64
#define BM 32
#define NKT 64

// ws float offsets
#define WS_DENOM 0
#define WS_PROXY 64
#define WS_COUNT 128
#define WS_META  256            // float4 per token: 65536 floats
#define WS_WST   65792          // 524288 ushorts = 1 MB, W f16 2-plane frag-linear

typedef __attribute__((ext_vector_type(8))) _Float16 f16x8;
typedef __attribute__((ext_vector_type(16))) float f32x16;

__global__ void init_kernel(float* ws) {
    int i = threadIdx.x;
    if (i < 192) ws[i] = 0.0f;
}

// W [4096][64] f32 -> wst: per kt (64), 16 fragments of 1 KB in glds-linear order.
//   slot = frag*64 + lane, frag = s*4 + p*2 + eh  (s:kstep 0..3, p:plane, eh:expert half)
//   wst[kt*8192 + slot*8 + j] = plane-p f16 of 4096*W[kt*64 + s*16 + (lane>>5)*8 + j][eh*32 + (lane&31)]
__global__ __launch_bounds__(256) void wconv(const float* __restrict__ W,
                                             ushort* __restrict__ wst) {
    __shared__ float t[64][68];
    const int kt = blockIdx.x, tid = threadIdx.x;
    #pragma unroll
    for (int i = 0; i < 4; i++) {
        int idx = tid + i * 256;
        int r = idx >> 4, c4 = idx & 15;
        float4 v = *(const float4*)(W + (size_t)(kt * 64 + r) * NE + c4 * 4);
        *(float4*)(&t[r][c4 * 4]) = v;
    }
    __syncthreads();
    #pragma unroll
    for (int it = 0; it < 4; it++) {
        int slot = it * 256 + tid;          // 0..1023
        int frag = slot >> 6, lane = slot & 63;
        int s = frag >> 2, p = (frag >> 1) & 1, eh = frag & 1;
        int e  = eh * 32 + (lane & 31);
        int kl = s * 16 + (lane >> 5) * 8;
        f16x8 o;
        #pragma unroll
        for (int j = 0; j < 8; j++) {
            float f = 4096.0f * t[kl + j][e];
            _Float16 hh = (_Float16)f;
            o[j] = p ? (_Float16)(f - (float)hh) : hh;
        }
        *(f16x8*)(wst + (size_t)kt * 8192 + (size_t)slot * 8) = o;
    }
}

// LDS per buffer (24576 B): x planes [0,8192): row*256 + p*128 + chunk^(row&7) * 16
//                           W frags   [8192,24576): 8192 + slot*16  (glds-linear)
__global__ __launch_bounds__(256, 2) void gate_main(const float* __restrict__ x,
        const ushort* __restrict__ wst, const float* __restrict__ bias,
        float* __restrict__ ws) {

    __shared__ __align__(16) char smem[2][24576];
    __shared__ float tmax[BM], tinv[BM];
    __shared__ float pp[4][NE];

    const int tid = threadIdx.x, wave = tid >> 6, lane = tid & 63;
    const int l31 = lane & 31, khf = lane >> 5;
    const int eh = wave & 1;           // expert half
    const int kh = wave >> 1;          // K half
    const int tb = blockIdx.x * BM;

    // x staging: thread -> row sr (0..31), chunk sc (0..7, 8 floats)
    const int sr = tid >> 3, sc = tid & 7;
    const float* xp = x + (size_t)(tb + sr) * DIM + sc * 8;
    const uint xw0 = (uint)sr * 256 + (uint)((sc ^ (sr & 7)) * 16);

    f32x16 acc;
    #pragma unroll
    for (int i = 0; i < 16; i++) acc[i] = 0.0f;

    float4 cx0, cx1;

    auto issue_x = [&](int kt) {
        const float* p = xp + kt * 64;
        cx0 = *(const float4*)p;
        cx1 = *(const float4*)(p + 4);
    };
    auto issue_w = [&](char* B, int kt) {
        #pragma unroll
        for (int q = 0; q < 4; q++)
            __builtin_amdgcn_global_load_lds(
                (const __attribute__((address_space(1))) uint*)
                    (wst + (size_t)kt * 8192 + q * 2048 + tid * 8),
                (__attribute__((address_space(3))) uint*)
                    (B + 8192 + q * 4096 + tid * 16), 16, 0, 0);
    };
    auto split_write = [&](char* B) {
        float f[8] = {cx0.x, cx0.y, cx0.z, cx0.w, cx1.x, cx1.y, cx1.z, cx1.w};
        f16x8 h, m;
        #pragma unroll
        for (int j = 0; j < 8; j++) {
            float v = 512.0f * f[j];
            _Float16 hh = (_Float16)v;
            h[j] = hh;
            m[j] = (_Float16)(v - (float)hh);
        }
        *(f16x8*)(B + xw0) = h;
        *(f16x8*)(B + xw0 + 128) = m;
    };
    auto compute = [&](const char* B) {
        #pragma unroll
        for (int si = 0; si < 2; si++) {
            int s = kh * 2 + si;
            uint ca = (uint)l31 * 256 + (uint)((((s * 2 + khf)) ^ (l31 & 7)) * 16);
            f16x8 ah = *(const f16x8*)(B + ca);
            f16x8 am = *(const f16x8*)(B + ca + 128);
            const char* Wb = B + 8192 + (size_t)(s * 4 + eh) * 1024 + lane * 16;
            f16x8 wh = *(const f16x8*)(Wb);
            f16x8 wm = *(const f16x8*)(Wb + 2048);
            acc = __builtin_amdgcn_mfma_f32_32x32x16_f16(ah, wh, acc, 0, 0, 0);
            acc = __builtin_amdgcn_mfma_f32_32x32x16_f16(am, wh, acc, 0, 0, 0);
            acc = __builtin_amdgcn_mfma_f32_32x32x16_f16(ah, wm, acc, 0, 0, 0);
        }
    };

    // prologue
    issue_x(0);
    issue_w(smem[0], 0);
    split_write(smem[0]);      // waits x(0); W glds keep flying
    __syncthreads();           // drains W(0)

    for (int kt = 0; kt < NKT; kt++) {
        char* cur = smem[kt & 1];
        char* nxt = smem[(kt & 1) ^ 1];
        if (kt + 1 < NKT) {
            issue_x(kt + 1);       // HBM loads, consumed after compute
            issue_w(nxt, kt + 1);  // glds, drained at barrier
        }
        compute(cur);
        if (kt + 1 < NKT) split_write(nxt);
        __syncthreads();
    }

    // epilogue: lg aliased onto buf0 (last used at kt=62, safe after final barrier)
    float* lgf = (float*)smem[0];     // lg[32][68]
    const float scale = 1.0f / 2097152.0f;   // 2^-21 = 1/(512*4096)
    {
        int col = eh * 32 + l31;
        if (kh == 0) {
            float b = bias[col];
            #pragma unroll
            for (int r = 0; r < 16; r++) {
                int row = (r & 3) + 8 * (r >> 2) + 4 * khf;
                lgf[row * 68 + col] = acc[r] * scale + b;
            }
        }
    }
    __syncthreads();
    {
        int col = eh * 32 + l31;
        if (kh == 1) {
            #pragma unroll
            for (int r = 0; r < 16; r++) {
                int row = (r & 3) + 8 * (r >> 2) + 4 * khf;
                lgf[row * 68 + col] += acc[r] * scale;
            }
        }
    }
    __syncthreads();

    // per-token softmax + top-2 (threads 0..31)
    if (tid < BM) {
        const int t = tid;
        float m = -INFINITY;
        #pragma unroll
        for (int e = 0; e < NE; e++) m = fmaxf(m, lgf[t * 68 + e]);
        float s = 0.0f;
        float v0 = -INFINITY, v1 = -INFINITY;
        int i0 = 0, i1 = 1;
        #pragma unroll
        for (int e = 0; e < NE; e++) {
            float l = lgf[t * 68 + e];
            s += expf(l - m);
            if (l > v0) { v1 = v0; i1 = i0; v0 = l; i0 = e; }
            else if (l > v1) { v1 = l; i1 = e; }
        }
        float inv = 1.0f / s;
        tmax[t] = m; tinv[t] = inv;
        float g0 = expf(v0 - m) * inv;
        float g1 = expf(v1 - m) * inv;
        float4 mt4;
        mt4.x = __int_as_float(i0);
        mt4.y = __int_as_float(i1);
        mt4.z = g0; mt4.w = g1;
        ((float4*)(ws + WS_META))[tb + t] = mt4;
        atomicAdd(&ws[WS_DENOM + i0], g0);
        atomicAdd(&ws[WS_DENOM + i1], g1);
        atomicAdd(&ws[WS_COUNT + i0], 1.0f);
        atomicAdd(&ws[WS_COUNT + i1], 1.0f);
    }
    __syncthreads();

    // per-expert gate-score partial sums (density_proxy numerator)
    {
        int e = tid & 63;
        int grp = tid >> 6;    // 0..3, 8 tokens each
        float p = 0.0f;
        #pragma unroll
        for (int r = 0; r < 8; r++) {
            int t = grp * 8 + r;
            p += expf(lgf[t * 68 + e] - tmax[t]) * tinv[t];
        }
        pp[grp][e] = p;
    }
    __syncthreads();
    if (tid < NE) {
        float s = pp[0][tid] + pp[1][tid] + pp[2][tid] + pp[3][tid];
        atomicAdd(&ws[WS_PROXY + tid], s);
    }
}

__global__ __launch_bounds__(256) void gate_write(const float* __restrict__ ws,
                                                  float* __restrict__ out) {
    const float CAP = 16384.0f;
    int tid = threadIdx.x;
    int tl = tid >> 4;
    int e4 = (tid & 15) * 4;
    int t = blockIdx.x * 16 + tl;
    float4 mt = ((const float4*)(ws + WS_META))[t];
    int i0 = __float_as_int(mt.x), i1 = __float_as_int(mt.y);
    float s0 = mt.z * CAP / (ws[i0] + 1e-6f);
    float s1 = mt.w * CAP / (ws[i1] + 1e-6f);
    float4 v = {0.0f, 0.0f, 0.0f, 0.0f};
    float* vp = (float*)&v;
    #pragma unroll
    for (int j = 0; j < 4; j++) {
        int e = e4 + j;
        vp[j] = (e == i0) ? s0 : ((e == i1) ? s1 : 0.0f);
    }
    *(float4*)(out + (size_t)t * NE + e4) = v;
}

__global__ void gate_loss(const float* __restrict__ ws, float* __restrict__ out) {
    int e = threadIdx.x;
    float v = ws[WS_PROXY + e] * ws[WS_COUNT + e];
    #pragma unroll
    for (int off = 32; off; off >>= 1) v += __shfl_down(v, off);
    if (e == 0) {
        out[(size_t)TOKENS * NE] = 64.0f * v / (16384.0f * 16384.0f);
    }
}

extern "C" void kernel_launch(void* const* d_in, const int* in_sizes, int n_in,
                              void* d_out, int out_size, void* d_ws, size_t ws_size,
                              hipStream_t stream) {
    const float* x = (const float*)d_in[0];
    const float* W = (const float*)d_in[1];
    const float* b = (const float*)d_in[2];
    float* out = (float*)d_out;
    float* ws = (float*)d_ws;
    ushort* wst = (ushort*)(ws + WS_WST);

    hipLaunchKernelGGL(init_kernel, dim3(1), dim3(256), 0, stream, ws);
    hipLaunchKernelGGL(wconv, dim3(64), dim3(256), 0, stream, W, wst);
    hipLaunchKernelGGL(gate_main, dim3(TOKENS / BM), dim3(256), 0, stream,
                       x, wst, b, ws);
    hipLaunchKernelGGL(gate_write, dim3(TOKENS / 16), dim3(256), 0, stream, ws, out);
    hipLaunchKernelGGL(gate_loss, dim3(1), dim3(64), 0, stream, ws, out);
}

// Round 8
// 95.008 us; speedup vs baseline: 1.7806x; 1.7806x over previous
//
#include <hip/hip_runtime.h>
#include <math.h>

#define TOKENS 16384
#define DIM 4096
#define NE 64
#define BM 32
#define NKT 64
#define NBLK 512

// ws float offsets
#define WS_META  256                       // float4 per token: 65536 floats
#define WS_PART  65792                     // 512 blocks x 192 floats
#define WS_WST   164096                    // 524288 ushorts = W f16 2-plane frag-linear

typedef __attribute__((ext_vector_type(8))) _Float16 f16x8;
typedef __attribute__((ext_vector_type(16))) float f32x16;

// W [4096][64] f32 -> wst: per kt (64), 16 fragments of 1 KB in glds-linear order.
//   slot = frag*64 + lane, frag = s*4 + p*2 + eh  (s:kstep 0..3, p:plane, eh:expert half)
//   wst[kt*8192 + slot*8 + j] = plane-p f16 of 4096*W[kt*64 + s*16 + (lane>>5)*8 + j][eh*32 + (lane&31)]
__global__ __launch_bounds__(256) void wconv(const float* __restrict__ W,
                                             ushort* __restrict__ wst) {
    __shared__ float t[64][68];
    const int kt = blockIdx.x, tid = threadIdx.x;
    #pragma unroll
    for (int i = 0; i < 4; i++) {
        int idx = tid + i * 256;
        int r = idx >> 4, c4 = idx & 15;
        float4 v = *(const float4*)(W + (size_t)(kt * 64 + r) * NE + c4 * 4);
        *(float4*)(&t[r][c4 * 4]) = v;
    }
    __syncthreads();
    #pragma unroll
    for (int it = 0; it < 4; it++) {
        int slot = it * 256 + tid;          // 0..1023
        int frag = slot >> 6, lane = slot & 63;
        int s = frag >> 2, p = (frag >> 1) & 1, eh = frag & 1;
        int e  = eh * 32 + (lane & 31);
        int kl = s * 16 + (lane >> 5) * 8;
        f16x8 o;
        #pragma unroll
        for (int j = 0; j < 8; j++) {
            float f = 4096.0f * t[kl + j][e];
            _Float16 hh = (_Float16)f;
            o[j] = p ? (_Float16)(f - (float)hh) : hh;
        }
        *(f16x8*)(wst + (size_t)kt * 8192 + (size_t)slot * 8) = o;
    }
}

// LDS buffer (24576 B):
//   x f32 [0,8192):  off(r,cs) = (r>>3)*2048 + (cs&1)*1024 + (r&7)*128 + (cs>>1)*16
//                    stored chunk cs holds logical chunk c = (cs&1) | (((cs>>1)^(r&7))<<1)
//   W     [8192,24576): 8192 + slot*16 (glds-linear, frag layout per wconv)
__global__ __launch_bounds__(256, 2) void gate_main(const float* __restrict__ x,
        const ushort* __restrict__ wst, const float* __restrict__ bias,
        float* __restrict__ ws) {

    __shared__ __align__(16) char smem[2][24576];
    __shared__ float tmax[BM], tinv[BM];
    __shared__ float pp[4][NE];
    __shared__ float sg0[BM], sg1[BM];
    __shared__ int   si0[BM], si1[BM];

    const int tid = threadIdx.x, wave = tid >> 6, lane = tid & 63;
    const int l31 = lane & 31, khf = lane >> 5;
    const int eh = wave & 1;           // expert half
    const int kh = wave >> 1;          // K half
    const int tb = blockIdx.x * BM;
    const int blk = blockIdx.x;

    f32x16 acc;
    #pragma unroll
    for (int i = 0; i < 16; i++) acc[i] = 0.0f;

    auto issue_x = [&](char* B, int kt) {
        #pragma unroll
        for (int q = 0; q < 2; q++) {
            int cs = ((lane & 7) << 1) | q;              // stored chunk
            int r  = (wave << 3) | (lane >> 3);          // row 0..31
            int cl = (cs & 1) | ((((cs >> 1) ^ (r & 7))) << 1);
            const float* src = x + (size_t)(tb + r) * DIM + kt * 64 + cl * 4;
            __builtin_amdgcn_global_load_lds(
                (const __attribute__((address_space(1))) uint*)src,
                (__attribute__((address_space(3))) uint*)
                    (B + wave * 2048 + q * 1024 + lane * 16), 16, 0, 0);
        }
    };
    auto issue_w = [&](char* B, int kt) {
        #pragma unroll
        for (int q = 0; q < 4; q++)
            __builtin_amdgcn_global_load_lds(
                (const __attribute__((address_space(1))) uint*)
                    (wst + (size_t)kt * 8192 + q * 2048 + tid * 8),
                (__attribute__((address_space(3))) uint*)
                    (B + 8192 + q * 4096 + tid * 16), 16, 0, 0);
    };
    auto compute = [&](const char* B) {
        #pragma unroll
        for (int si = 0; si < 2; si++) {
            int s = kh * 2 + si;
            int c0 = s * 4 + khf * 2;                    // even logical chunk
            uint cs_hi = (uint)((c0 >> 1) ^ (l31 & 7));
            uint base = (uint)(l31 >> 3) * 2048 + (uint)(l31 & 7) * 128 + cs_hi * 16;
            float4 A0 = *(const float4*)(B + base);
            float4 A1 = *(const float4*)(B + base + 1024);
            f16x8 ah, am;
            {
                float f[8] = {A0.x, A0.y, A0.z, A0.w, A1.x, A1.y, A1.z, A1.w};
                #pragma unroll
                for (int j = 0; j < 8; j++) {
                    float v = 512.0f * f[j];
                    _Float16 hh = (_Float16)v;
                    ah[j] = hh;
                    am[j] = (_Float16)(v - (float)hh);
                }
            }
            const char* Wb = B + 8192 + (size_t)(s * 4 + eh) * 1024 + lane * 16;
            f16x8 wh = *(const f16x8*)(Wb);
            f16x8 wm = *(const f16x8*)(Wb + 2048);
            acc = __builtin_amdgcn_mfma_f32_32x32x16_f16(ah, wh, acc, 0, 0, 0);
            acc = __builtin_amdgcn_mfma_f32_32x32x16_f16(am, wh, acc, 0, 0, 0);
            acc = __builtin_amdgcn_mfma_f32_32x32x16_f16(ah, wm, acc, 0, 0, 0);
        }
    };

    // prologue
    issue_x(smem[0], 0);
    issue_w(smem[0], 0);
    __syncthreads();

    for (int kt = 0; kt < NKT; kt++) {
        char* cur = smem[kt & 1];
        char* nxt = smem[(kt & 1) ^ 1];
        if (kt + 1 < NKT) {
            issue_x(nxt, kt + 1);
            issue_w(nxt, kt + 1);
        }
        compute(cur);
        __syncthreads();
    }

    // epilogue: logits into LDS (aliased onto buf0)
    float* lgf = (float*)smem[0];     // lg[32][68]
    const float scale = 1.0f / 2097152.0f;   // 2^-21 = 1/(512*4096)
    {
        int col = eh * 32 + l31;
        if (kh == 0) {
            float b = bias[col];
            #pragma unroll
            for (int r = 0; r < 16; r++) {
                int row = (r & 3) + 8 * (r >> 2) + 4 * khf;
                lgf[row * 68 + col] = acc[r] * scale + b;
            }
        }
    }
    __syncthreads();
    {
        int col = eh * 32 + l31;
        if (kh == 1) {
            #pragma unroll
            for (int r = 0; r < 16; r++) {
                int row = (r & 3) + 8 * (r >> 2) + 4 * khf;
                lgf[row * 68 + col] += acc[r] * scale;
            }
        }
    }
    __syncthreads();

    // per-token softmax + top-2 (threads 0..31) — no atomics, stash picks in LDS
    if (tid < BM) {
        const int t = tid;
        float m = -INFINITY;
        #pragma unroll
        for (int e = 0; e < NE; e++) m = fmaxf(m, lgf[t * 68 + e]);
        float s = 0.0f;
        float v0 = -INFINITY, v1 = -INFINITY;
        int i0 = 0, i1 = 1;
        #pragma unroll
        for (int e = 0; e < NE; e++) {
            float l = lgf[t * 68 + e];
            s += expf(l - m);
            if (l > v0) { v1 = v0; i1 = i0; v0 = l; i0 = e; }
            else if (l > v1) { v1 = l; i1 = e; }
        }
        float inv = 1.0f / s;
        tmax[t] = m; tinv[t] = inv;
        float g0 = expf(v0 - m) * inv;
        float g1 = expf(v1 - m) * inv;
        sg0[t] = g0; sg1[t] = g1; si0[t] = i0; si1[t] = i1;
        float4 mt4;
        mt4.x = __int_as_float(i0);
        mt4.y = __int_as_float(i1);
        mt4.z = g0; mt4.w = g1;
        ((float4*)(ws + WS_META))[tb + t] = mt4;
    }
    __syncthreads();

    // per-expert gate-score partial sums (density_proxy numerator)
    {
        int e = tid & 63;
        int grp = tid >> 6;    // 0..3, 8 tokens each
        float p = 0.0f;
        #pragma unroll
        for (int r = 0; r < 8; r++) {
            int t = grp * 8 + r;
            p += expf(lgf[t * 68 + e] - tmax[t]) * tinv[t];
        }
        pp[grp][e] = p;
    }
    __syncthreads();

    // deterministic per-block partials: [blk][0:64)=denom, [64:128)=proxy, [128:192)=count
    if (tid < NE) {
        int e = tid;
        float d = 0.0f, c = 0.0f;
        #pragma unroll
        for (int t = 0; t < BM; t++) {
            if (si0[t] == e) { d += sg0[t]; c += 1.0f; }
            if (si1[t] == e) { d += sg1[t]; c += 1.0f; }
        }
        float pr = pp[0][e] + pp[1][e] + pp[2][e] + pp[3][e];
        float* P = ws + WS_PART + (size_t)blk * 192;
        P[e]       = d;
        P[64 + e]  = pr;
        P[128 + e] = c;
    }
}

// finals: ws[0:64)=denom, ws[64:128)=proxy, ws[128:192)=count
__global__ __launch_bounds__(64) void gate_reduce(const float* __restrict__ part,
                                                  float* __restrict__ ws) {
    const int f = blockIdx.x;      // 0..191
    const int lane = threadIdx.x;  // 0..63
    float s = 0.0f;
    #pragma unroll
    for (int j = 0; j < 8; j++)
        s += part[(size_t)(lane * 8 + j) * 192 + f];
    #pragma unroll
    for (int off = 32; off; off >>= 1) s += __shfl_down(s, off);
    if (lane == 0) ws[f] = s;
}

__global__ __launch_bounds__(256) void gate_write(const float* __restrict__ ws,
                                                  float* __restrict__ out) {
    const float CAP = 16384.0f;
    int tid = threadIdx.x;
    int tl = tid >> 4;
    int e4 = (tid & 15) * 4;
    int t = blockIdx.x * 16 + tl;
    float4 mt = ((const float4*)(ws + WS_META))[t];
    int i0 = __float_as_int(mt.x), i1 = __float_as_int(mt.y);
    float s0 = mt.z * CAP / (ws[i0] + 1e-6f);
    float s1 = mt.w * CAP / (ws[i1] + 1e-6f);
    float4 v = {0.0f, 0.0f, 0.0f, 0.0f};
    float* vp = (float*)&v;
    #pragma unroll
    for (int j = 0; j < 4; j++) {
        int e = e4 + j;
        vp[j] = (e == i0) ? s0 : ((e == i1) ? s1 : 0.0f);
    }
    *(float4*)(out + (size_t)t * NE + e4) = v;
}

__global__ void gate_loss(const float* __restrict__ ws, float* __restrict__ out) {
    int e = threadIdx.x;
    float v = ws[64 + e] * ws[128 + e];
    #pragma unroll
    for (int off = 32; off; off >>= 1) v += __shfl_down(v, off);
    if (e == 0) {
        out[(size_t)TOKENS * NE] = 64.0f * v / (16384.0f * 16384.0f);
    }
}

extern "C" void kernel_launch(void* const* d_in, const int* in_sizes, int n_in,
                              void* d_out, int out_size, void* d_ws, size_t ws_size,
                              hipStream_t stream) {
    const float* x = (const float*)d_in[0];
    const float* W = (const float*)d_in[1];
    const float* b = (const float*)d_in[2];
    float* out = (float*)d_out;
    float* ws = (float*)d_ws;
    ushort* wst = (ushort*)(ws + WS_WST);

    hipLaunchKernelGGL(wconv, dim3(64), dim3(256), 0, stream, W, wst);
    hipLaunchKernelGGL(gate_main, dim3(NBLK), dim3(256), 0, stream, x, wst, b, ws);
    hipLaunchKernelGGL(gate_reduce, dim3(192), dim3(64), 0, stream,
                       ws + WS_PART, ws);
    hipLaunchKernelGGL(gate_write, dim3(TOKENS / 16), dim3(256), 0, stream, ws, out);
    hipLaunchKernelGGL(gate_loss, dim3(1), dim3(64), 0, stream, ws, out);
}